// Round 14
// baseline (6628.699 us; speedup 1.0000x reference)
//
#include <hip/hip_runtime.h>
#include <stdint.h>

// ScannedRNN: T=1024, B=128, D=512 GRU with resets + straight-through clip.
// prep -> gemmA (gi = x@Wi+bi, bf16) -> rnnB (persistent 128-block recurrent
// kernel; Wh in VGPRs; h exchanged as tagged bf16 words (epoch<<16|bf16),
// 2-slot parity). DUAL-PUBLISH: sc0 L2 inbox (fast, same-XCD) + relaxed
// agent mirror (authoritative, r5-proven). r13 canary gate polls the INBOX;
// verify-fetch from inbox (tag-checked => staleness is slow, never wrong);
// bounded timeouts + 3-strike sticky fallback to the mirror path.

typedef float f32x4 __attribute__((ext_vector_type(4)));
typedef short s16x8 __attribute__((ext_vector_type(8)));

#define DD 512
#define BB 128
#define TT 1024

static __device__ __forceinline__ unsigned short f2bf(float f) {
  uint32_t u = __builtin_bit_cast(uint32_t, f);
  u = (u + 0x7fffu + ((u >> 16) & 1u)) >> 16;   // RNE
  return (unsigned short)u;
}
static __device__ __forceinline__ float b2f(uint32_t bits) {
  return __builtin_bit_cast(float, bits << 16);
}
static __device__ __forceinline__ s16x8 ldsfrag(const char* p) {
  return __builtin_bit_cast(s16x8, *reinterpret_cast<const uint4*>(p));
}

// ---------------- prep: convert weights to bf16, packed layouts ----------------
__global__ void prep(const float* __restrict__ Wi, const float* __restrict__ Whrz,
                     const float* __restrict__ Whn,
                     unsigned short* __restrict__ WiT, unsigned short* __restrict__ Wpk) {
  int i = blockIdx.x * 256 + threadIdx.x;
  if (i < 786432) {
    int n = i >> 9, k = i & 511;
    WiT[i] = f2bf(Wi[(size_t)k * 1536 + n]);
  } else {
    int j = i - 786432;
    int ck = j >> 9;
    int k = j & 511;
    int cj = ck / 96, c96 = ck % 96;
    int g = c96 >> 5, cc = c96 & 31;
    float v = (g < 2) ? Whrz[(size_t)k * 1024 + g * 512 + cj * 32 + cc]
                      : Whn[(size_t)k * 512 + cj * 32 + cc];
    Wpk[j] = f2bf(v);
  }
}

// ---------------- tag0: mirror slot0 <- tagged(epoch 0) h0; f32 mirror <- h0 ----
__global__ void tag0(const float* __restrict__ h0, uint32_t* __restrict__ hxt,
                     float* __restrict__ hbF) {
  int i = blockIdx.x * 512 + threadIdx.x;   // 65536
  float v = h0[i];
  hxt[i] = (uint32_t)f2bf(v);               // tag 0
  hbF[i] = v;
}

// ---------------- resets dtype probe (bool bytes vs int32) ----------------
__global__ void scanR(const int* __restrict__ r, int* __restrict__ flag) {
  int i = blockIdx.x * 256 + threadIdx.x;       // 32768 ints = 131072 bytes, safe
  unsigned int v = (unsigned int)r[i];
  if (v > 1u) atomicOr(flag, 1);
}

// ---------------- gemmA: gi[M][1536] = x[M][512] @ Wi + bi (bf16 out) ----------------
__global__ __launch_bounds__(256) void gemmA(const float* __restrict__ x,
                                             const unsigned short* __restrict__ WiT,
                                             const float* __restrict__ bi,
                                             unsigned short* __restrict__ gi) {
  __shared__ unsigned short Al[128 * 64];
  __shared__ unsigned short Bl[128 * 64];
  const int tid = threadIdx.x;
  const int lane = tid & 63;
  const int wv = tid >> 6;
  const int wm = wv >> 1, wn = wv & 1;
  const int n0 = blockIdx.x * 128;
  const int m0 = blockIdx.y * 128;

  const int sr = tid >> 1;
  const int sh = tid & 1;
  const float* xp = x + (size_t)(m0 + sr) * DD + sh * 32;
  const unsigned short* wp = WiT + (size_t)(n0 + sr) * DD + sh * 32;

  float bir[4];
#pragma unroll
  for (int j = 0; j < 4; ++j) bir[j] = bi[n0 + wn * 64 + j * 16 + (lane & 15)];

  f32x4 acc[4][4];
#pragma unroll
  for (int i = 0; i < 4; ++i)
#pragma unroll
    for (int j = 0; j < 4; ++j) acc[i][j] = (f32x4){0.f, 0.f, 0.f, 0.f};

  float4 xa[8];
  uint4 wa[4];
#pragma unroll
  for (int q = 0; q < 8; ++q) xa[q] = *reinterpret_cast<const float4*>(xp + q * 4);
#pragma unroll
  for (int c = 0; c < 4; ++c) wa[c] = *reinterpret_cast<const uint4*>(wp + c * 8);

  for (int kt = 0; kt < 8; ++kt) {
    __syncthreads();
    const int swz = (sr & 7) << 4;
#pragma unroll
    for (int c = 0; c < 4; ++c) {
      const float4 a = xa[2 * c], b = xa[2 * c + 1];
      uint4 u;
      u.x = (uint32_t)f2bf(a.x) | ((uint32_t)f2bf(a.y) << 16);
      u.y = (uint32_t)f2bf(a.z) | ((uint32_t)f2bf(a.w) << 16);
      u.z = (uint32_t)f2bf(b.x) | ((uint32_t)f2bf(b.y) << 16);
      u.w = (uint32_t)f2bf(b.z) | ((uint32_t)f2bf(b.w) << 16);
      const int off = sr * 128 + ((sh * 64 + c * 16) ^ swz);
      *reinterpret_cast<uint4*>(reinterpret_cast<char*>(Al) + off) = u;
    }
#pragma unroll
    for (int c = 0; c < 4; ++c) {
      const int off = sr * 128 + ((sh * 64 + c * 16) ^ swz);
      *reinterpret_cast<uint4*>(reinterpret_cast<char*>(Bl) + off) = wa[c];
    }
    if (kt < 7) {
#pragma unroll
      for (int q = 0; q < 8; ++q)
        xa[q] = *reinterpret_cast<const float4*>(xp + (kt + 1) * 64 + q * 4);
#pragma unroll
      for (int c = 0; c < 4; ++c)
        wa[c] = *reinterpret_cast<const uint4*>(wp + (kt + 1) * 64 + c * 8);
    }
    __syncthreads();
#pragma unroll
    for (int kk = 0; kk < 2; ++kk) {
      s16x8 af[4], bfr[4];
      const int kb = kk * 64 + ((lane >> 4) << 4);
      const int sw = (lane & 7) << 4;
#pragma unroll
      for (int i = 0; i < 4; ++i) {
        const int row = wm * 64 + i * 16 + (lane & 15);
        af[i] = ldsfrag(reinterpret_cast<const char*>(Al) + row * 128 + (kb ^ sw));
      }
#pragma unroll
      for (int j = 0; j < 4; ++j) {
        const int row = wn * 64 + j * 16 + (lane & 15);
        bfr[j] = ldsfrag(reinterpret_cast<const char*>(Bl) + row * 128 + (kb ^ sw));
      }
#pragma unroll
      for (int i = 0; i < 4; ++i)
#pragma unroll
        for (int j = 0; j < 4; ++j)
          acc[i][j] = __builtin_amdgcn_mfma_f32_16x16x32_bf16(af[i], bfr[j], acc[i][j], 0, 0, 0);
    }
  }
#pragma unroll
  for (int i = 0; i < 4; ++i) {
    const int gr0 = m0 + wm * 64 + i * 16 + ((lane >> 4) << 2);
#pragma unroll
    for (int j = 0; j < 4; ++j) {
      const int gc = n0 + wn * 64 + j * 16 + (lane & 15);
#pragma unroll
      for (int r = 0; r < 4; ++r)
        gi[(size_t)(gr0 + r) * 1536 + gc] = f2bf(acc[i][j][r] + bir[j]);
    }
  }
}

// ---------------- rnnB helpers ----------------
static __device__ __forceinline__ unsigned rmask16f(const int* resets, int rmode,
                                                    long long tg, int row0) {
  unsigned m = 0;
  if (rmode) {
    const unsigned char* rb = reinterpret_cast<const unsigned char*>(resets);
    uint4 u = *reinterpret_cast<const uint4*>(rb + (size_t)tg * 128 + row0);
    unsigned w0 = u.x, w1 = u.y, w2 = u.z, w3 = u.w;
#pragma unroll
    for (int b = 0; b < 4; ++b) {
      if ((w0 >> (8 * b)) & 0xFFu) m |= 1u << (0 + b);
      if ((w1 >> (8 * b)) & 0xFFu) m |= 1u << (4 + b);
      if ((w2 >> (8 * b)) & 0xFFu) m |= 1u << (8 + b);
      if ((w3 >> (8 * b)) & 0xFFu) m |= 1u << (12 + b);
    }
  } else {
    const uint4* p = reinterpret_cast<const uint4*>(resets + (size_t)tg * 128 + row0);
#pragma unroll
    for (int q = 0; q < 4; ++q) {
      uint4 u = p[q];
      if (u.x) m |= 1u << (q * 4 + 0);
      if (u.y) m |= 1u << (q * 4 + 1);
      if (u.z) m |= 1u << (q * 4 + 2);
      if (u.w) m |= 1u << (q * 4 + 3);
    }
  }
  return m;
}

// authoritative mirror poll (r5-proven): relaxed-agent loads -> ballot
static __device__ __forceinline__ void pollTag(const uint32_t* src, unsigned exp,
                                               unsigned short (&v)[16]) {
  for (int it = 0; it < (1 << 16); ++it) {
    uint32_t u[16];
#pragma unroll
    for (int i = 0; i < 16; ++i)
      u[i] = __hip_atomic_load(src + (size_t)i * 512,
                               __ATOMIC_RELAXED, __HIP_MEMORY_SCOPE_AGENT);
    unsigned bad = 0;
#pragma unroll
    for (int i = 0; i < 16; ++i) bad |= ((u[i] >> 16) ^ exp);
    if (__ballot(bad != 0u) == 0ull) {
#pragma unroll
      for (int i = 0; i < 16; ++i) v[i] = (unsigned short)u[i];
      return;
    }
    __builtin_amdgcn_s_sleep(1);
  }
#pragma unroll
  for (int i = 0; i < 16; ++i) v[i] = 0;   // watchdog fall-through (unreachable)
}

// inbox verify-fetch: 16 sc0 loads (L1-bypass, L2-fresh), tag-checked, bounded.
static __device__ __forceinline__ bool pollInbox(const uint32_t* src, unsigned exp,
                                                 unsigned short (&v)[16], int tries) {
  const uint32_t* b0 = src;          const uint32_t* b1 = src + 1024;
  const uint32_t* b2 = src + 2048;   const uint32_t* b3 = src + 3072;
  const uint32_t* b4 = src + 4096;   const uint32_t* b5 = src + 5120;
  const uint32_t* b6 = src + 6144;   const uint32_t* b7 = src + 7168;
  for (int it = 0; it < tries; ++it) {
    uint32_t u[16];
    asm volatile(
        "global_load_dword %0, %16, off sc0\n\t"
        "global_load_dword %1, %16, off offset:2048 sc0\n\t"
        "global_load_dword %2, %17, off sc0\n\t"
        "global_load_dword %3, %17, off offset:2048 sc0\n\t"
        "global_load_dword %4, %18, off sc0\n\t"
        "global_load_dword %5, %18, off offset:2048 sc0\n\t"
        "global_load_dword %6, %19, off sc0\n\t"
        "global_load_dword %7, %19, off offset:2048 sc0\n\t"
        "global_load_dword %8, %20, off sc0\n\t"
        "global_load_dword %9, %20, off offset:2048 sc0\n\t"
        "global_load_dword %10, %21, off sc0\n\t"
        "global_load_dword %11, %21, off offset:2048 sc0\n\t"
        "global_load_dword %12, %22, off sc0\n\t"
        "global_load_dword %13, %22, off offset:2048 sc0\n\t"
        "global_load_dword %14, %23, off sc0\n\t"
        "global_load_dword %15, %23, off offset:2048 sc0\n\t"
        "s_waitcnt vmcnt(0)"
        : "=&v"(u[0]), "=&v"(u[1]), "=&v"(u[2]), "=&v"(u[3]),
          "=&v"(u[4]), "=&v"(u[5]), "=&v"(u[6]), "=&v"(u[7]),
          "=&v"(u[8]), "=&v"(u[9]), "=&v"(u[10]), "=&v"(u[11]),
          "=&v"(u[12]), "=&v"(u[13]), "=&v"(u[14]), "=&v"(u[15])
        : "v"(b0), "v"(b1), "v"(b2), "v"(b3), "v"(b4), "v"(b5), "v"(b6), "v"(b7)
        : "memory");
    unsigned bad = 0;
#pragma unroll
    for (int i = 0; i < 16; ++i) bad |= ((u[i] >> 16) ^ exp);
    if (__ballot(bad != 0u) == 0ull) {
#pragma unroll
      for (int i = 0; i < 16; ++i) v[i] = (unsigned short)u[i];
      return true;
    }
    if (it >= 1) __builtin_amdgcn_s_sleep(1);
  }
  return false;
}

// ---------------- rnnB: persistent recurrent kernel ----------------
// 128 blocks = 16 col-blocks (cj) x 8 row groups (rg; bid%8 -> same-XCD set
// under round-robin). Wh in VGPRs. h exchange: tagged word, 2-slot parity,
// dual-published to hxl (sc0 inbox) and hxt (agent mirror). Canary gate
// (wave 0, inbox) -> verify-fetch (inbox) -> mirror fallback; 3-strike
// sticky disable of the inbox path per block.
__global__ __launch_bounds__(512) void rnnB(const unsigned short* __restrict__ gi,
                                            const unsigned short* __restrict__ Wpk,
                                            const float* __restrict__ bhn,
                                            const int* __restrict__ resets,
                                            uint32_t* hxt,                 // mirror [2][128][512]
                                            uint32_t* hxl,                 // inbox  [2][128][512]
                                            float* hbF,                    // [128][512]
                                            const int* __restrict__ rmodep,
                                            float* __restrict__ ys,
                                            int t0, int tc) {
  __shared__ char Hlb[16384];     // h(t) bf16 [16 rows][512 cols], xor-swizzled
  __shared__ float ax[6528];      // partials [8][3][16*17]
  __shared__ int sGot;

  const int tid = threadIdx.x;
  const int lane = tid & 63;
  const int wv = tid >> 6;
  const int w = wv & 1, ks = wv >> 1;
  const int cj = blockIdx.x >> 3, rg = blockIdx.x & 7;
  const int ec = tid & 31, eb = tid >> 5;          // elementwise: col-in-32, row-in-16
  const int bglob = rg * 16 + eb;
  const int colglob = cj * 32 + ec;
  const int rmode = *rmodep;

  // ---- Wh fragments -> registers (once per launch) ----
  uint4 wreg[3][4];
  {
    const unsigned short* wbase = Wpk + (size_t)cj * 96 * 512
                                + (size_t)(w * 16 + (lane & 15)) * 512
                                + ks * 128 + (lane >> 4) * 8;
#pragma unroll
    for (int g = 0; g < 3; ++g)
#pragma unroll
      for (int kk = 0; kk < 4; ++kk)
        wreg[g][kk] = *reinterpret_cast<const uint4*>(wbase + g * 32 * 512 + kk * 32);
  }

  const float bhn_c = bhn[colglob];
  float h_old = hbF[(size_t)bglob * 512 + colglob];   // f32 carry at chunk start

  // ---- initial h(t0): mirror poll (written by tag0 / prev chunk) ----
  unsigned short v[16];
  pollTag(hxt + (size_t)(t0 & 1) * 65536 + (size_t)rg * 8192 + tid, (unsigned)t0 & 0xFFFFu, v);

  unsigned mask = rmask16f(resets, rmode, t0, rg * 16);
  uint32_t gir, giz, gin;
  {
    const unsigned short* gp = gi + (size_t)bglob * 1536 + colglob;  // chunk-local t=0
    gir = gp[0]; giz = gp[512]; gin = gp[1024];
  }

  // precomputed LDS stage offsets (thread column tid, row i)
  int soff[16];
#pragma unroll
  for (int i = 0; i < 16; ++i)
    soff[i] = i * 1024 + (((((tid * 2) >> 4) ^ (i & 7)) << 4) | ((tid & 7) * 2));

  bool useL2 = true;
  int failc = 0;

  for (int t = 0; t < tc; ++t) {
    const long long tg = t0 + t;
    // ---- stage Hl: thread owns column tid, rows 0..15; reset-masked ----
#pragma unroll
    for (int i = 0; i < 16; ++i) {
      unsigned short x = ((mask >> i) & 1u) ? (unsigned short)0 : v[i];
      *reinterpret_cast<unsigned short*>(Hlb + soff[i]) = x;
    }
    __syncthreads();  // B1: Hl ready
    // ---- MFMA: W frags from VGPR, H frags from LDS ----
    f32x4 acc[3];
#pragma unroll
    for (int g = 0; g < 3; ++g) acc[g] = (f32x4){0.f, 0.f, 0.f, 0.f};
    {
      const int rowb = lane & 15;
      const char* hrow = Hlb + rowb * 1024;
      const int hsw = (rowb & 7) << 4;
      const int kplusB = (lane >> 4) << 4;
      s16x8 hfrag[4];
#pragma unroll
      for (int kk = 0; kk < 4; ++kk) {
        const int kbB = (ks * 128 + kk * 32) * 2 + kplusB;
        hfrag[kk] = ldsfrag(hrow + (kbB ^ hsw));
      }
#pragma unroll
      for (int g = 0; g < 3; ++g)
#pragma unroll
        for (int kk = 0; kk < 4; ++kk)
          acc[g] = __builtin_amdgcn_mfma_f32_16x16x32_bf16(
              __builtin_bit_cast(s16x8, wreg[g][kk]), hfrag[kk], acc[g], 0, 0, 0);
    }
    {  // partials -> LDS (padded stride 17)
      const int mh = (lane >> 4) << 2, nn = lane & 15;
#pragma unroll
      for (int g = 0; g < 3; ++g) {
        float* dst = ax + ((ks * 2 + w) * 3 + g) * 272 + nn;
#pragma unroll
        for (int r = 0; r < 4; ++r) dst[(mh + r) * 17] = acc[g][r];
      }
    }
    __syncthreads();  // B2: ax ready; also fences Hl reads vs next stage
    // ---- elementwise GRU update: one (row eb, col ec) per thread ----
    {
      const int wc = ec >> 4, mc = ec & 15;
      float s0a = 0.f, s1a = 0.f, s2a = 0.f;
#pragma unroll
      for (int k2 = 0; k2 < 4; ++k2) {
        const float* p = ax + ((k2 * 2 + wc) * 3) * 272 + mc * 17 + eb;
        s0a += p[0]; s1a += p[272]; s2a += p[544];
      }
      const float r = 1.f / (1.f + __expf(-(b2f(gir) + s0a)));
      const float z = 1.f / (1.f + __expf(-(b2f(giz) + s1a)));
      const float hu = ((mask >> eb) & 1u) ? 0.f : h_old;
      const float pre = b2f(gin) + r * (s2a + bhn_c);
      const float n = 1.f - 2.f / (1.f + __expf(2.f * pre));
      float hn = (1.f - z) * n + z * hu;
      hn = fminf(1.f, fmaxf(-1.f, hn));
      __builtin_nontemporal_store(hn, ys + ((size_t)tg * 128 + bglob) * 512 + colglob);
      // dual publish to slot (tg+1)&1: sc0 inbox first, then agent mirror
      const uint32_t tagged = (((uint32_t)(tg + 1) & 0xFFFFu) << 16) | (uint32_t)f2bf(hn);
      const size_t poff = (size_t)((tg + 1) & 1) * 65536 + (size_t)bglob * 512 + colglob;
      asm volatile("global_store_dword %0, %1, off sc0"
                   :: "v"(hxl + poff), "v"(tagged) : "memory");
      __hip_atomic_store(hxt + poff, tagged, __ATOMIC_RELAXED, __HIP_MEMORY_SCOPE_AGENT);
      if (t == tc - 1) hbF[(size_t)bglob * 512 + colglob] = hn;   // f32 carry for next chunk
      h_old = hn;
    }
    if (t + 1 < tc) {
      // prefetch next step's gi + resets (drains at the canary-gate barrier)
      const unsigned short* gp = gi + ((size_t)(t + 1) * 128 + bglob) * 1536 + colglob;
      uint32_t ngr = gp[0], ngz = gp[512], ngn = gp[1024];
      unsigned nmask = rmask16f(resets, rmode, tg + 1, rg * 16);
      const unsigned exp = (unsigned)(tg + 1) & 0xFFFFu;
      const size_t slotoff = (size_t)((tg + 1) & 1) * 65536;
      // ---- canary gate: wave 0, lanes 0-15 poll one INBOX word per producer ----
      if (wv == 0) {
        int g = 0;
        if (useL2) {
          const uint32_t* cp = hxl + slotoff + (size_t)(rg * 16 + 15) * 512
                             + (lane & 15) * 32 + 31;
          bool ok = (lane >= 16);
          for (int it = 0; it < 64; ++it) {
            if (!ok) {
              uint32_t u;
              asm volatile("global_load_dword %0, %1, off sc0\n\ts_waitcnt vmcnt(0)"
                           : "=v"(u) : "v"(cp) : "memory");
              ok = ((u >> 16) == exp);
            }
            if (__ballot(ok ? 0 : 1) == 0ull) { g = 1; break; }
            if (it >= 2) __builtin_amdgcn_s_sleep(1);
          }
        }
        if (lane == 0) sGot = g;
      }
      __syncthreads();  // gate: waves 1-7 park (quiet fabric); gi prefetch drained
      const bool fast = useL2 && (sGot != 0);
      bool done = false;
      if (fast)
        done = pollInbox(hxl + slotoff + (size_t)rg * 8192 + tid, exp, v, 64);
      if (!done)
        pollTag(hxt + slotoff + (size_t)rg * 8192 + tid, exp, v);   // authoritative
      if (useL2) {
        if (fast) failc = 0;
        else if (++failc >= 3) useL2 = false;   // sticky disable (uniform: from sGot)
      }
      gir = ngr; giz = ngz; gin = ngn; mask = nmask;
    }
  }
}

// ---------------- launch ----------------
extern "C" void kernel_launch(void* const* d_in, const int* in_sizes, int n_in,
                              void* d_out, int out_size, void* d_ws, size_t ws_size,
                              hipStream_t stream) {
  const float* h0 = (const float*)d_in[0];
  const float* ins = (const float*)d_in[1];
  const int* rst = (const int*)d_in[2];
  const float* Wi = (const float*)d_in[3];
  const float* bi = (const float*)d_in[4];
  const float* Whrz = (const float*)d_in[5];
  const float* Whn = (const float*)d_in[6];
  const float* bhn = (const float*)d_in[7];
  float* ys = (float*)d_out;

  char* ws = (char*)d_ws;
  unsigned short* WiT = (unsigned short*)(ws);              // 1,572,864 B
  unsigned short* Wpk = (unsigned short*)(ws + 1572864);    // 1,572,864 B
  uint32_t* hxt = (uint32_t*)(ws + 3145728);                //   524,288 B (mirror)
  uint32_t* hxl = (uint32_t*)(ws + 3670016);                //   524,288 B (L2 inbox)
  float* hbF = (float*)(ws + 4194304);                      //   262,144 B
  int* flag = (int*)(ws + 4456448);                         //         4 B (rmode)
  const size_t gi_off = 4460544;
  unsigned short* gi = (unsigned short*)(ws + gi_off);

  size_t avail = (ws_size > gi_off) ? (ws_size - gi_off) : 0;
  long long tcap = (long long)(avail / (128ull * 1536ull * 2ull));
  int Tc = (int)((tcap > 1024) ? 1024 : tcap);
  Tc &= ~1;
  if (Tc < 2) Tc = 2;

  hipMemsetAsync(flag, 0, 4, stream);                                  // rmode
  hipMemsetAsync(hxt, 0, 1048576, stream);       // mirror + inbox -> tag 0 (replay-safe)
  tag0<<<dim3(128), dim3(512), 0, stream>>>(h0, hxt, hbF);             // slot0 = h(0)
  prep<<<dim3(6144), dim3(256), 0, stream>>>(Wi, Whrz, Whn, WiT, Wpk);
  scanR<<<dim3(128), dim3(256), 0, stream>>>(rst, flag);

  for (int t0 = 0; t0 < 1024; t0 += Tc) {
    int tc = 1024 - t0;
    if (tc > Tc) tc = Tc;
    gemmA<<<dim3(12, tc), dim3(256), 0, stream>>>(ins + (size_t)t0 * 65536, WiT, bi, gi);
    rnnB<<<dim3(128), dim3(512), 0, stream>>>(gi, Wpk, bhn, rst, hxt, hxl, hbF,
                                              flag, ys, t0, tc);
  }
}

// Round 15
// 3750.794 us; speedup vs baseline: 1.7673x; 1.7673x over previous
//
#include <hip/hip_runtime.h>
#include <stdint.h>

// ScannedRNN: T=1024, B=128, D=512 GRU with resets + straight-through clip.
// prep -> xcvt (x f32->bf16 once) -> gemmA (gi = x@Wi+bi, all-bf16 staging)
// -> rnnB (r13-proven: persistent 128-block recurrent kernel; Wh in VGPRs;
// tagged-word 2-slot relaxed-agent h exchange; canary gate + verify-fetch).

typedef float f32x4 __attribute__((ext_vector_type(4)));
typedef short s16x8 __attribute__((ext_vector_type(8)));

#define DD 512
#define BB 128
#define TT 1024

static __device__ __forceinline__ unsigned short f2bf(float f) {
  uint32_t u = __builtin_bit_cast(uint32_t, f);
  u = (u + 0x7fffu + ((u >> 16) & 1u)) >> 16;   // RNE
  return (unsigned short)u;
}
static __device__ __forceinline__ float b2f(uint32_t bits) {
  return __builtin_bit_cast(float, bits << 16);
}
static __device__ __forceinline__ s16x8 ldsfrag(const char* p) {
  return __builtin_bit_cast(s16x8, *reinterpret_cast<const uint4*>(p));
}

// ---------------- prep: convert weights to bf16, packed layouts ----------------
__global__ void prep(const float* __restrict__ Wi, const float* __restrict__ Whrz,
                     const float* __restrict__ Whn,
                     unsigned short* __restrict__ WiT, unsigned short* __restrict__ Wpk) {
  int i = blockIdx.x * 256 + threadIdx.x;
  if (i < 786432) {
    int n = i >> 9, k = i & 511;
    WiT[i] = f2bf(Wi[(size_t)k * 1536 + n]);
  } else {
    int j = i - 786432;
    int ck = j >> 9;
    int k = j & 511;
    int cj = ck / 96, c96 = ck % 96;
    int g = c96 >> 5, cc = c96 & 31;
    float v = (g < 2) ? Whrz[(size_t)k * 1024 + g * 512 + cj * 32 + cc]
                      : Whn[(size_t)k * 512 + cj * 32 + cc];
    Wpk[j] = f2bf(v);
  }
}

// ---------------- xcvt: chunk of x (f32) -> bf16, one pass ----------------
__global__ void xcvt(const float* __restrict__ x, unsigned short* __restrict__ xb,
                     int n8) {
  int i = blockIdx.x * 256 + threadIdx.x;     // one uint4 (8 bf16) per thread
  if (i >= n8) return;
  const float4* p = reinterpret_cast<const float4*>(x) + (size_t)i * 2;
  float4 a = p[0], b = p[1];
  uint4 u;
  u.x = (uint32_t)f2bf(a.x) | ((uint32_t)f2bf(a.y) << 16);
  u.y = (uint32_t)f2bf(a.z) | ((uint32_t)f2bf(a.w) << 16);
  u.z = (uint32_t)f2bf(b.x) | ((uint32_t)f2bf(b.y) << 16);
  u.w = (uint32_t)f2bf(b.z) | ((uint32_t)f2bf(b.w) << 16);
  reinterpret_cast<uint4*>(xb)[i] = u;
}

// ---------------- tag0: mirror slot0 <- tagged(epoch 0) h0; f32 mirror <- h0 ----
__global__ void tag0(const float* __restrict__ h0, uint32_t* __restrict__ hxt,
                     float* __restrict__ hbF) {
  int i = blockIdx.x * 512 + threadIdx.x;   // 65536
  float v = h0[i];
  hxt[i] = (uint32_t)f2bf(v);               // tag 0
  hbF[i] = v;
}

// ---------------- resets dtype probe (bool bytes vs int32) ----------------
__global__ void scanR(const int* __restrict__ r, int* __restrict__ flag) {
  int i = blockIdx.x * 256 + threadIdx.x;       // 32768 ints = 131072 bytes, safe
  unsigned int v = (unsigned int)r[i];
  if (v > 1u) atomicOr(flag, 1);
}

// ---------------- gemmA: gi[M][1536] = xb[M][512] @ Wi + bi (all bf16) ----------------
__global__ __launch_bounds__(256) void gemmA(const unsigned short* __restrict__ xb,
                                             const unsigned short* __restrict__ WiT,
                                             const float* __restrict__ bi,
                                             unsigned short* __restrict__ gi) {
  __shared__ unsigned short Al[128 * 64];
  __shared__ unsigned short Bl[128 * 64];
  const int tid = threadIdx.x;
  const int lane = tid & 63;
  const int wv = tid >> 6;
  const int wm = wv >> 1, wn = wv & 1;
  const int n0 = blockIdx.x * 128;
  const int m0 = blockIdx.y * 128;

  const int sr = tid >> 1;
  const int sh = tid & 1;
  const unsigned short* xp = xb + (size_t)(m0 + sr) * DD + sh * 32;
  const unsigned short* wp = WiT + (size_t)(n0 + sr) * DD + sh * 32;

  float bir[4];
#pragma unroll
  for (int j = 0; j < 4; ++j) bir[j] = bi[n0 + wn * 64 + j * 16 + (lane & 15)];

  f32x4 acc[4][4];
#pragma unroll
  for (int i = 0; i < 4; ++i)
#pragma unroll
    for (int j = 0; j < 4; ++j) acc[i][j] = (f32x4){0.f, 0.f, 0.f, 0.f};

  uint4 xa[4], wa[4];
#pragma unroll
  for (int c = 0; c < 4; ++c) {
    xa[c] = *reinterpret_cast<const uint4*>(xp + c * 8);
    wa[c] = *reinterpret_cast<const uint4*>(wp + c * 8);
  }

  for (int kt = 0; kt < 8; ++kt) {
    __syncthreads();
    const int swz = (sr & 7) << 4;
#pragma unroll
    for (int c = 0; c < 4; ++c) {
      const int off = sr * 128 + ((sh * 64 + c * 16) ^ swz);
      *reinterpret_cast<uint4*>(reinterpret_cast<char*>(Al) + off) = xa[c];
      *reinterpret_cast<uint4*>(reinterpret_cast<char*>(Bl) + off) = wa[c];
    }
    if (kt < 7) {
#pragma unroll
      for (int c = 0; c < 4; ++c) {
        xa[c] = *reinterpret_cast<const uint4*>(xp + (kt + 1) * 64 + c * 8);
        wa[c] = *reinterpret_cast<const uint4*>(wp + (kt + 1) * 64 + c * 8);
      }
    }
    __syncthreads();
#pragma unroll
    for (int kk = 0; kk < 2; ++kk) {
      s16x8 af[4], bfr[4];
      const int kb = kk * 64 + ((lane >> 4) << 4);
      const int sw = (lane & 7) << 4;
#pragma unroll
      for (int i = 0; i < 4; ++i) {
        const int row = wm * 64 + i * 16 + (lane & 15);
        af[i] = ldsfrag(reinterpret_cast<const char*>(Al) + row * 128 + (kb ^ sw));
      }
#pragma unroll
      for (int j = 0; j < 4; ++j) {
        const int row = wn * 64 + j * 16 + (lane & 15);
        bfr[j] = ldsfrag(reinterpret_cast<const char*>(Bl) + row * 128 + (kb ^ sw));
      }
#pragma unroll
      for (int i = 0; i < 4; ++i)
#pragma unroll
        for (int j = 0; j < 4; ++j)
          acc[i][j] = __builtin_amdgcn_mfma_f32_16x16x32_bf16(af[i], bfr[j], acc[i][j], 0, 0, 0);
    }
  }
#pragma unroll
  for (int i = 0; i < 4; ++i) {
    const int gr0 = m0 + wm * 64 + i * 16 + ((lane >> 4) << 2);
#pragma unroll
    for (int j = 0; j < 4; ++j) {
      const int gc = n0 + wn * 64 + j * 16 + (lane & 15);
#pragma unroll
      for (int r = 0; r < 4; ++r)
        gi[(size_t)(gr0 + r) * 1536 + gc] = f2bf(acc[i][j][r] + bir[j]);
    }
  }
}

// ---------------- rnnB helpers ----------------
static __device__ __forceinline__ unsigned rmask16f(const int* resets, int rmode,
                                                    long long tg, int row0) {
  unsigned m = 0;
  if (rmode) {
    const unsigned char* rb = reinterpret_cast<const unsigned char*>(resets);
    uint4 u = *reinterpret_cast<const uint4*>(rb + (size_t)tg * 128 + row0);
    unsigned w0 = u.x, w1 = u.y, w2 = u.z, w3 = u.w;
#pragma unroll
    for (int b = 0; b < 4; ++b) {
      if ((w0 >> (8 * b)) & 0xFFu) m |= 1u << (0 + b);
      if ((w1 >> (8 * b)) & 0xFFu) m |= 1u << (4 + b);
      if ((w2 >> (8 * b)) & 0xFFu) m |= 1u << (8 + b);
      if ((w3 >> (8 * b)) & 0xFFu) m |= 1u << (12 + b);
    }
  } else {
    const uint4* p = reinterpret_cast<const uint4*>(resets + (size_t)tg * 128 + row0);
#pragma unroll
    for (int q = 0; q < 4; ++q) {
      uint4 u = p[q];
      if (u.x) m |= 1u << (q * 4 + 0);
      if (u.y) m |= 1u << (q * 4 + 1);
      if (u.z) m |= 1u << (q * 4 + 2);
      if (u.w) m |= 1u << (q * 4 + 3);
    }
  }
  return m;
}

// batched branch-free tag poll: 16 coalesced agent loads -> single wait ->
// ballot; v[i] = low 16 bits once tag matches. (authoritative)
static __device__ __forceinline__ void pollTag(const uint32_t* src, unsigned exp,
                                               unsigned short (&v)[16]) {
  for (int it = 0; it < (1 << 16); ++it) {
    uint32_t u[16];
#pragma unroll
    for (int i = 0; i < 16; ++i)
      u[i] = __hip_atomic_load(src + (size_t)i * 512,
                               __ATOMIC_RELAXED, __HIP_MEMORY_SCOPE_AGENT);
    unsigned bad = 0;
#pragma unroll
    for (int i = 0; i < 16; ++i) bad |= ((u[i] >> 16) ^ exp);
    if (__ballot(bad != 0u) == 0ull) {
#pragma unroll
      for (int i = 0; i < 16; ++i) v[i] = (unsigned short)u[i];
      return;
    }
    __builtin_amdgcn_s_sleep(1);
  }
#pragma unroll
  for (int i = 0; i < 16; ++i) v[i] = 0;   // watchdog fall-through (unreachable)
}

// ---------------- rnnB: persistent recurrent kernel (r13-proven) ----------------
// 128 blocks = 16 col-blocks (cj) x 8 row groups (rg). Wh slice in VGPRs.
// h exchange: hxt [2][128][512] u32 = (epoch16<<16)|bf16(h), slot (tg+1)&1.
// 2-slot + exact tag is overwrite-safe. Poll = canary gate (wave 0 polls one
// word per producer; other waves park at barrier -> fabric stays quiet) then
// a single verify-fetch pass (authoritative pollTag).
__global__ __launch_bounds__(512) void rnnB(const unsigned short* __restrict__ gi,
                                            const unsigned short* __restrict__ Wpk,
                                            const float* __restrict__ bhn,
                                            const int* __restrict__ resets,
                                            uint32_t* hxt,                 // [2][128][512]
                                            float* hbF,                    // [128][512]
                                            const int* __restrict__ rmodep,
                                            float* __restrict__ ys,
                                            int t0, int tc) {
  __shared__ char Hlb[16384];     // h(t) bf16 [16 rows][512 cols], xor-swizzled
  __shared__ float ax[6528];      // partials [8][3][16*17]

  const int tid = threadIdx.x;
  const int lane = tid & 63;
  const int wv = tid >> 6;
  const int w = wv & 1, ks = wv >> 1;
  const int cj = blockIdx.x >> 3, rg = blockIdx.x & 7;
  const int ec = tid & 31, eb = tid >> 5;          // elementwise: col-in-32, row-in-16
  const int bglob = rg * 16 + eb;
  const int colglob = cj * 32 + ec;
  const int rmode = *rmodep;

  // ---- Wh fragments -> registers (once per launch) ----
  uint4 wreg[3][4];
  {
    const unsigned short* wbase = Wpk + (size_t)cj * 96 * 512
                                + (size_t)(w * 16 + (lane & 15)) * 512
                                + ks * 128 + (lane >> 4) * 8;
#pragma unroll
    for (int g = 0; g < 3; ++g)
#pragma unroll
      for (int kk = 0; kk < 4; ++kk)
        wreg[g][kk] = *reinterpret_cast<const uint4*>(wbase + g * 32 * 512 + kk * 32);
  }

  const float bhn_c = bhn[colglob];
  float h_old = hbF[(size_t)bglob * 512 + colglob];   // f32 carry at chunk start

  // ---- initial h(t0) bf16 panel: poll slot t0&1 for tag t0 (already present) ----
  unsigned short v[16];
  pollTag(hxt + (size_t)(t0 & 1) * 65536 + (size_t)rg * 8192 + tid, (unsigned)t0 & 0xFFFFu, v);

  unsigned mask = rmask16f(resets, rmode, t0, rg * 16);
  uint32_t gir, giz, gin;
  {
    const unsigned short* gp = gi + (size_t)bglob * 1536 + colglob;  // chunk-local t=0
    gir = gp[0]; giz = gp[512]; gin = gp[1024];
  }

  // precomputed LDS stage offsets (thread column tid, row i)
  int soff[16];
#pragma unroll
  for (int i = 0; i < 16; ++i)
    soff[i] = i * 1024 + (((((tid * 2) >> 4) ^ (i & 7)) << 4) | ((tid & 7) * 2));

  for (int t = 0; t < tc; ++t) {
    const long long tg = t0 + t;
    // ---- stage Hl: thread owns column tid, rows 0..15; reset-masked ----
#pragma unroll
    for (int i = 0; i < 16; ++i) {
      unsigned short x = ((mask >> i) & 1u) ? (unsigned short)0 : v[i];
      *reinterpret_cast<unsigned short*>(Hlb + soff[i]) = x;
    }
    __syncthreads();  // B1: Hl ready
    // ---- MFMA: W frags from VGPR, H frags from LDS ----
    f32x4 acc[3];
#pragma unroll
    for (int g = 0; g < 3; ++g) acc[g] = (f32x4){0.f, 0.f, 0.f, 0.f};
    {
      const int rowb = lane & 15;
      const char* hrow = Hlb + rowb * 1024;
      const int hsw = (rowb & 7) << 4;
      const int kplusB = (lane >> 4) << 4;
      s16x8 hfrag[4];
#pragma unroll
      for (int kk = 0; kk < 4; ++kk) {
        const int kbB = (ks * 128 + kk * 32) * 2 + kplusB;
        hfrag[kk] = ldsfrag(hrow + (kbB ^ hsw));
      }
#pragma unroll
      for (int g = 0; g < 3; ++g)
#pragma unroll
        for (int kk = 0; kk < 4; ++kk)
          acc[g] = __builtin_amdgcn_mfma_f32_16x16x32_bf16(
              __builtin_bit_cast(s16x8, wreg[g][kk]), hfrag[kk], acc[g], 0, 0, 0);
    }
    {  // partials -> LDS (padded stride 17)
      const int mh = (lane >> 4) << 2, nn = lane & 15;
#pragma unroll
      for (int g = 0; g < 3; ++g) {
        float* dst = ax + ((ks * 2 + w) * 3 + g) * 272 + nn;
#pragma unroll
        for (int r = 0; r < 4; ++r) dst[(mh + r) * 17] = acc[g][r];
      }
    }
    __syncthreads();  // B2: ax ready; also fences Hl reads vs next stage
    // ---- elementwise GRU update: one (row eb, col ec) per thread ----
    {
      const int wc = ec >> 4, mc = ec & 15;
      float s0a = 0.f, s1a = 0.f, s2a = 0.f;
#pragma unroll
      for (int k2 = 0; k2 < 4; ++k2) {
        const float* p = ax + ((k2 * 2 + wc) * 3) * 272 + mc * 17 + eb;
        s0a += p[0]; s1a += p[272]; s2a += p[544];
      }
      const float r = 1.f / (1.f + __expf(-(b2f(gir) + s0a)));
      const float z = 1.f / (1.f + __expf(-(b2f(giz) + s1a)));
      const float hu = ((mask >> eb) & 1u) ? 0.f : h_old;
      const float pre = b2f(gin) + r * (s2a + bhn_c);
      const float n = 1.f - 2.f / (1.f + __expf(2.f * pre));
      float hn = (1.f - z) * n + z * hu;
      hn = fminf(1.f, fmaxf(-1.f, hn));
      __builtin_nontemporal_store(hn, ys + ((size_t)tg * 128 + bglob) * 512 + colglob);
      // tagged bf16 publish to slot (tg+1)&1
      const uint32_t tagged = (((uint32_t)(tg + 1) & 0xFFFFu) << 16) | (uint32_t)f2bf(hn);
      uint32_t* hp = hxt + (size_t)((tg + 1) & 1) * 65536 + (size_t)bglob * 512 + colglob;
      __hip_atomic_store(hp, tagged, __ATOMIC_RELAXED, __HIP_MEMORY_SCOPE_AGENT);
      if (t == tc - 1) hbF[(size_t)bglob * 512 + colglob] = hn;   // f32 carry for next chunk
      h_old = hn;
    }
    if (t + 1 < tc) {
      // prefetch next step's gi + resets (drains at the canary barrier)
      const unsigned short* gp = gi + ((size_t)(t + 1) * 128 + bglob) * 1536 + colglob;
      uint32_t ngr = gp[0], ngz = gp[512], ngn = gp[1024];
      unsigned nmask = rmask16f(resets, rmode, tg + 1, rg * 16);
      const unsigned exp = (unsigned)(tg + 1) & 0xFFFFu;
      const size_t slotoff = (size_t)((tg + 1) & 1) * 65536;
      // ---- canary gate: wave 0, lanes 0-15 poll one word per producer ----
      if (wv == 0) {
        const uint32_t* cp = hxt + slotoff + (size_t)(rg * 16 + 15) * 512
                           + (lane & 15) * 32 + 31;
        bool ok = (lane >= 16);
        for (int it = 0; it < (1 << 14); ++it) {
          if (!ok)
            ok = ((__hip_atomic_load(cp, __ATOMIC_RELAXED,
                                     __HIP_MEMORY_SCOPE_AGENT) >> 16) == exp);
          if (__ballot(ok ? 0 : 1) == 0ull) break;
          __builtin_amdgcn_s_sleep(1);
        }
      }
      __syncthreads();  // gate: waves 1-7 idle here (quiet fabric); gi drained
      // ---- verify-fetch (authoritative, usually 1 iteration) ----
      pollTag(hxt + slotoff + (size_t)rg * 8192 + tid, exp, v);
      gir = ngr; giz = ngz; gin = ngn; mask = nmask;
    }
  }
}

// ---------------- launch ----------------
extern "C" void kernel_launch(void* const* d_in, const int* in_sizes, int n_in,
                              void* d_out, int out_size, void* d_ws, size_t ws_size,
                              hipStream_t stream) {
  const float* h0 = (const float*)d_in[0];
  const float* ins = (const float*)d_in[1];
  const int* rst = (const int*)d_in[2];
  const float* Wi = (const float*)d_in[3];
  const float* bi = (const float*)d_in[4];
  const float* Whrz = (const float*)d_in[5];
  const float* Whn = (const float*)d_in[6];
  const float* bhn = (const float*)d_in[7];
  float* ys = (float*)d_out;

  char* ws = (char*)d_ws;
  unsigned short* WiT = (unsigned short*)(ws);              // 1,572,864 B
  unsigned short* Wpk = (unsigned short*)(ws + 1572864);    // 1,572,864 B
  uint32_t* hxt = (uint32_t*)(ws + 3145728);                //   524,288 B ([2][128][512])
  float* hbF = (float*)(ws + 3670016);                      //   262,144 B ([128][512])
  int* flag = (int*)(ws + 3932160);                         //         4 B (rmode)
  const size_t dyn_off = 3936256;

  // per-step: xbf 131072 B + gi 393216 B
  size_t avail = (ws_size > dyn_off) ? (ws_size - dyn_off) : 0;
  long long tcap = (long long)(avail / 524288ull);
  int Tc = (int)((tcap > 1024) ? 1024 : tcap);
  Tc &= ~1;
  if (Tc < 2) Tc = 2;
  unsigned short* xbf = (unsigned short*)(ws + dyn_off);
  unsigned short* gi = (unsigned short*)(ws + dyn_off + (size_t)Tc * 131072);

  hipMemsetAsync(flag, 0, 4, stream);                                  // rmode
  hipMemsetAsync(hxt, 0, 524288, stream);        // both slots -> tag 0 (replay-safe)
  tag0<<<dim3(128), dim3(512), 0, stream>>>(h0, hxt, hbF);             // slot0 = h(0)
  prep<<<dim3(6144), dim3(256), 0, stream>>>(Wi, Whrz, Whn, WiT, Wpk);
  scanR<<<dim3(128), dim3(256), 0, stream>>>(rst, flag);

  for (int t0 = 0; t0 < 1024; t0 += Tc) {
    int tc = 1024 - t0;
    if (tc > Tc) tc = Tc;
    const int n8 = tc * 8192;                                // uint4s in chunk
    xcvt<<<dim3((n8 + 255) / 256), dim3(256), 0, stream>>>(ins + (size_t)t0 * 65536,
                                                           xbf, n8);
    gemmA<<<dim3(12, tc), dim3(256), 0, stream>>>(xbf, WiT, bi, gi);
    rnnB<<<dim3(128), dim3(512), 0, stream>>>(gi, Wpk, bhn, rst, hxt, hbF, flag, ys, t0, tc);
  }
}

// Round 16
// 3442.175 us; speedup vs baseline: 1.9257x; 1.0897x over previous
//
#include <hip/hip_runtime.h>
#include <stdint.h>

// ScannedRNN: T=1024, B=128, D=512 GRU with resets + straight-through clip.
// prep (weight convert/pack) -> gemmA (gi = x@Wi+bi, bf16; f32->bf16 packing
// via v_cvt_pk_bf16_f32) -> rnnB (r13-proven: persistent 128-block recurrent
// kernel; Wh in VGPRs; tagged-word 2-slot relaxed-agent h exchange; canary
// gate + verify-fetch).

typedef float f32x4 __attribute__((ext_vector_type(4)));
typedef short s16x8 __attribute__((ext_vector_type(8)));

#define DD 512
#define BB 128
#define TT 1024

static __device__ __forceinline__ unsigned short f2bf(float f) {
  uint32_t u = __builtin_bit_cast(uint32_t, f);
  u = (u + 0x7fffu + ((u >> 16) & 1u)) >> 16;   // RNE
  return (unsigned short)u;
}
static __device__ __forceinline__ float b2f(uint32_t bits) {
  return __builtin_bit_cast(float, bits << 16);
}
static __device__ __forceinline__ s16x8 ldsfrag(const char* p) {
  return __builtin_bit_cast(s16x8, *reinterpret_cast<const uint4*>(p));
}
// HW RNE pack: lo16 = bf16(a), hi16 = bf16(b). Same rounding as f2bf.
static __device__ __forceinline__ uint32_t pk2(float a, float b) {
  uint32_t r;
  asm("v_cvt_pk_bf16_f32 %0, %1, %2" : "=v"(r) : "v"(a), "v"(b));
  return r;
}

// ---------------- prep: convert weights to bf16, packed layouts ----------------
__global__ void prep(const float* __restrict__ Wi, const float* __restrict__ Whrz,
                     const float* __restrict__ Whn,
                     unsigned short* __restrict__ WiT, unsigned short* __restrict__ Wpk) {
  int i = blockIdx.x * 256 + threadIdx.x;
  if (i < 786432) {
    int n = i >> 9, k = i & 511;
    WiT[i] = f2bf(Wi[(size_t)k * 1536 + n]);
  } else {
    int j = i - 786432;
    int ck = j >> 9;
    int k = j & 511;
    int cj = ck / 96, c96 = ck % 96;
    int g = c96 >> 5, cc = c96 & 31;
    float v = (g < 2) ? Whrz[(size_t)k * 1024 + g * 512 + cj * 32 + cc]
                      : Whn[(size_t)k * 512 + cj * 32 + cc];
    Wpk[j] = f2bf(v);
  }
}

// ---------------- tag0: mirror slot0 <- tagged(epoch 0) h0; f32 mirror <- h0 ----
__global__ void tag0(const float* __restrict__ h0, uint32_t* __restrict__ hxt,
                     float* __restrict__ hbF) {
  int i = blockIdx.x * 512 + threadIdx.x;   // 65536
  float v = h0[i];
  hxt[i] = (uint32_t)f2bf(v);               // tag 0
  hbF[i] = v;
}

// ---------------- resets dtype probe (bool bytes vs int32) ----------------
__global__ void scanR(const int* __restrict__ r, int* __restrict__ flag) {
  int i = blockIdx.x * 256 + threadIdx.x;       // 32768 ints = 131072 bytes, safe
  unsigned int v = (unsigned int)r[i];
  if (v > 1u) atomicOr(flag, 1);
}

// ---------------- gemmA: gi[M][1536] = x[M][512] @ Wi + bi (bf16 out) ----------------
__global__ __launch_bounds__(256) void gemmA(const float* __restrict__ x,
                                             const unsigned short* __restrict__ WiT,
                                             const float* __restrict__ bi,
                                             unsigned short* __restrict__ gi) {
  __shared__ unsigned short Al[128 * 64];
  __shared__ unsigned short Bl[128 * 64];
  const int tid = threadIdx.x;
  const int lane = tid & 63;
  const int wv = tid >> 6;
  const int wm = wv >> 1, wn = wv & 1;
  const int n0 = blockIdx.x * 128;
  const int m0 = blockIdx.y * 128;

  const int sr = tid >> 1;
  const int sh = tid & 1;
  const float* xp = x + (size_t)(m0 + sr) * DD + sh * 32;
  const unsigned short* wp = WiT + (size_t)(n0 + sr) * DD + sh * 32;

  float bir[4];
#pragma unroll
  for (int j = 0; j < 4; ++j) bir[j] = bi[n0 + wn * 64 + j * 16 + (lane & 15)];

  f32x4 acc[4][4];
#pragma unroll
  for (int i = 0; i < 4; ++i)
#pragma unroll
    for (int j = 0; j < 4; ++j) acc[i][j] = (f32x4){0.f, 0.f, 0.f, 0.f};

  float4 xa[8];
  uint4 wa[4];
#pragma unroll
  for (int q = 0; q < 8; ++q) xa[q] = *reinterpret_cast<const float4*>(xp + q * 4);
#pragma unroll
  for (int c = 0; c < 4; ++c) wa[c] = *reinterpret_cast<const uint4*>(wp + c * 8);

  for (int kt = 0; kt < 8; ++kt) {
    __syncthreads();
    const int swz = (sr & 7) << 4;
#pragma unroll
    for (int c = 0; c < 4; ++c) {
      const float4 a = xa[2 * c], b = xa[2 * c + 1];
      uint4 u;
      u.x = pk2(a.x, a.y);
      u.y = pk2(a.z, a.w);
      u.z = pk2(b.x, b.y);
      u.w = pk2(b.z, b.w);
      const int off = sr * 128 + ((sh * 64 + c * 16) ^ swz);
      *reinterpret_cast<uint4*>(reinterpret_cast<char*>(Al) + off) = u;
    }
#pragma unroll
    for (int c = 0; c < 4; ++c) {
      const int off = sr * 128 + ((sh * 64 + c * 16) ^ swz);
      *reinterpret_cast<uint4*>(reinterpret_cast<char*>(Bl) + off) = wa[c];
    }
    if (kt < 7) {
#pragma unroll
      for (int q = 0; q < 8; ++q)
        xa[q] = *reinterpret_cast<const float4*>(xp + (kt + 1) * 64 + q * 4);
#pragma unroll
      for (int c = 0; c < 4; ++c)
        wa[c] = *reinterpret_cast<const uint4*>(wp + (kt + 1) * 64 + c * 8);
    }
    __syncthreads();
#pragma unroll
    for (int kk = 0; kk < 2; ++kk) {
      s16x8 af[4], bfr[4];
      const int kb = kk * 64 + ((lane >> 4) << 4);
      const int sw = (lane & 7) << 4;
#pragma unroll
      for (int i = 0; i < 4; ++i) {
        const int row = wm * 64 + i * 16 + (lane & 15);
        af[i] = ldsfrag(reinterpret_cast<const char*>(Al) + row * 128 + (kb ^ sw));
      }
#pragma unroll
      for (int j = 0; j < 4; ++j) {
        const int row = wn * 64 + j * 16 + (lane & 15);
        bfr[j] = ldsfrag(reinterpret_cast<const char*>(Bl) + row * 128 + (kb ^ sw));
      }
#pragma unroll
      for (int i = 0; i < 4; ++i)
#pragma unroll
        for (int j = 0; j < 4; ++j)
          acc[i][j] = __builtin_amdgcn_mfma_f32_16x16x32_bf16(af[i], bfr[j], acc[i][j], 0, 0, 0);
    }
  }
#pragma unroll
  for (int i = 0; i < 4; ++i) {
    const int gr0 = m0 + wm * 64 + i * 16 + ((lane >> 4) << 2);
#pragma unroll
    for (int j = 0; j < 4; ++j) {
      const int gc = n0 + wn * 64 + j * 16 + (lane & 15);
#pragma unroll
      for (int r = 0; r < 4; ++r) {
        float s = acc[i][j][r] + bir[j];
        gi[(size_t)(gr0 + r) * 1536 + gc] = (unsigned short)pk2(s, s);
      }
    }
  }
}

// ---------------- rnnB helpers ----------------
static __device__ __forceinline__ unsigned rmask16f(const int* resets, int rmode,
                                                    long long tg, int row0) {
  unsigned m = 0;
  if (rmode) {
    const unsigned char* rb = reinterpret_cast<const unsigned char*>(resets);
    uint4 u = *reinterpret_cast<const uint4*>(rb + (size_t)tg * 128 + row0);
    unsigned w0 = u.x, w1 = u.y, w2 = u.z, w3 = u.w;
#pragma unroll
    for (int b = 0; b < 4; ++b) {
      if ((w0 >> (8 * b)) & 0xFFu) m |= 1u << (0 + b);
      if ((w1 >> (8 * b)) & 0xFFu) m |= 1u << (4 + b);
      if ((w2 >> (8 * b)) & 0xFFu) m |= 1u << (8 + b);
      if ((w3 >> (8 * b)) & 0xFFu) m |= 1u << (12 + b);
    }
  } else {
    const uint4* p = reinterpret_cast<const uint4*>(resets + (size_t)tg * 128 + row0);
#pragma unroll
    for (int q = 0; q < 4; ++q) {
      uint4 u = p[q];
      if (u.x) m |= 1u << (q * 4 + 0);
      if (u.y) m |= 1u << (q * 4 + 1);
      if (u.z) m |= 1u << (q * 4 + 2);
      if (u.w) m |= 1u << (q * 4 + 3);
    }
  }
  return m;
}

// batched branch-free tag poll: 16 coalesced agent loads -> single wait ->
// ballot; v[i] = low 16 bits once tag matches. (authoritative)
static __device__ __forceinline__ void pollTag(const uint32_t* src, unsigned exp,
                                               unsigned short (&v)[16]) {
  for (int it = 0; it < (1 << 16); ++it) {
    uint32_t u[16];
#pragma unroll
    for (int i = 0; i < 16; ++i)
      u[i] = __hip_atomic_load(src + (size_t)i * 512,
                               __ATOMIC_RELAXED, __HIP_MEMORY_SCOPE_AGENT);
    unsigned bad = 0;
#pragma unroll
    for (int i = 0; i < 16; ++i) bad |= ((u[i] >> 16) ^ exp);
    if (__ballot(bad != 0u) == 0ull) {
#pragma unroll
      for (int i = 0; i < 16; ++i) v[i] = (unsigned short)u[i];
      return;
    }
    __builtin_amdgcn_s_sleep(1);
  }
#pragma unroll
  for (int i = 0; i < 16; ++i) v[i] = 0;   // watchdog fall-through (unreachable)
}

// ---------------- rnnB: persistent recurrent kernel (r13-proven) ----------------
// 128 blocks = 16 col-blocks (cj) x 8 row groups (rg). Wh slice in VGPRs.
// h exchange: hxt [2][128][512] u32 = (epoch16<<16)|bf16(h), slot (tg+1)&1.
// 2-slot + exact tag is overwrite-safe. Poll = canary gate (wave 0 polls one
// word per producer; other waves park at barrier -> fabric stays quiet) then
// a single verify-fetch pass (authoritative pollTag).
__global__ __launch_bounds__(512) void rnnB(const unsigned short* __restrict__ gi,
                                            const unsigned short* __restrict__ Wpk,
                                            const float* __restrict__ bhn,
                                            const int* __restrict__ resets,
                                            uint32_t* hxt,                 // [2][128][512]
                                            float* hbF,                    // [128][512]
                                            const int* __restrict__ rmodep,
                                            float* __restrict__ ys,
                                            int t0, int tc) {
  __shared__ char Hlb[16384];     // h(t) bf16 [16 rows][512 cols], xor-swizzled
  __shared__ float ax[6528];      // partials [8][3][16*17]

  const int tid = threadIdx.x;
  const int lane = tid & 63;
  const int wv = tid >> 6;
  const int w = wv & 1, ks = wv >> 1;
  const int cj = blockIdx.x >> 3, rg = blockIdx.x & 7;
  const int ec = tid & 31, eb = tid >> 5;          // elementwise: col-in-32, row-in-16
  const int bglob = rg * 16 + eb;
  const int colglob = cj * 32 + ec;
  const int rmode = *rmodep;

  // ---- Wh fragments -> registers (once per launch) ----
  uint4 wreg[3][4];
  {
    const unsigned short* wbase = Wpk + (size_t)cj * 96 * 512
                                + (size_t)(w * 16 + (lane & 15)) * 512
                                + ks * 128 + (lane >> 4) * 8;
#pragma unroll
    for (int g = 0; g < 3; ++g)
#pragma unroll
      for (int kk = 0; kk < 4; ++kk)
        wreg[g][kk] = *reinterpret_cast<const uint4*>(wbase + g * 32 * 512 + kk * 32);
  }

  const float bhn_c = bhn[colglob];
  float h_old = hbF[(size_t)bglob * 512 + colglob];   // f32 carry at chunk start

  // ---- initial h(t0) bf16 panel: poll slot t0&1 for tag t0 (already present) ----
  unsigned short v[16];
  pollTag(hxt + (size_t)(t0 & 1) * 65536 + (size_t)rg * 8192 + tid, (unsigned)t0 & 0xFFFFu, v);

  unsigned mask = rmask16f(resets, rmode, t0, rg * 16);
  uint32_t gir, giz, gin;
  {
    const unsigned short* gp = gi + (size_t)bglob * 1536 + colglob;  // chunk-local t=0
    gir = gp[0]; giz = gp[512]; gin = gp[1024];
  }

  // precomputed LDS stage offsets (thread column tid, row i)
  int soff[16];
#pragma unroll
  for (int i = 0; i < 16; ++i)
    soff[i] = i * 1024 + (((((tid * 2) >> 4) ^ (i & 7)) << 4) | ((tid & 7) * 2));

  for (int t = 0; t < tc; ++t) {
    const long long tg = t0 + t;
    // ---- stage Hl: thread owns column tid, rows 0..15; reset-masked ----
#pragma unroll
    for (int i = 0; i < 16; ++i) {
      unsigned short x = ((mask >> i) & 1u) ? (unsigned short)0 : v[i];
      *reinterpret_cast<unsigned short*>(Hlb + soff[i]) = x;
    }
    __syncthreads();  // B1: Hl ready
    // ---- MFMA: W frags from VGPR, H frags from LDS ----
    f32x4 acc[3];
#pragma unroll
    for (int g = 0; g < 3; ++g) acc[g] = (f32x4){0.f, 0.f, 0.f, 0.f};
    {
      const int rowb = lane & 15;
      const char* hrow = Hlb + rowb * 1024;
      const int hsw = (rowb & 7) << 4;
      const int kplusB = (lane >> 4) << 4;
      s16x8 hfrag[4];
#pragma unroll
      for (int kk = 0; kk < 4; ++kk) {
        const int kbB = (ks * 128 + kk * 32) * 2 + kplusB;
        hfrag[kk] = ldsfrag(hrow + (kbB ^ hsw));
      }
#pragma unroll
      for (int g = 0; g < 3; ++g)
#pragma unroll
        for (int kk = 0; kk < 4; ++kk)
          acc[g] = __builtin_amdgcn_mfma_f32_16x16x32_bf16(
              __builtin_bit_cast(s16x8, wreg[g][kk]), hfrag[kk], acc[g], 0, 0, 0);
    }
    {  // partials -> LDS (padded stride 17)
      const int mh = (lane >> 4) << 2, nn = lane & 15;
#pragma unroll
      for (int g = 0; g < 3; ++g) {
        float* dst = ax + ((ks * 2 + w) * 3 + g) * 272 + nn;
#pragma unroll
        for (int r = 0; r < 4; ++r) dst[(mh + r) * 17] = acc[g][r];
      }
    }
    __syncthreads();  // B2: ax ready; also fences Hl reads vs next stage
    // ---- elementwise GRU update: one (row eb, col ec) per thread ----
    {
      const int wc = ec >> 4, mc = ec & 15;
      float s0a = 0.f, s1a = 0.f, s2a = 0.f;
#pragma unroll
      for (int k2 = 0; k2 < 4; ++k2) {
        const float* p = ax + ((k2 * 2 + wc) * 3) * 272 + mc * 17 + eb;
        s0a += p[0]; s1a += p[272]; s2a += p[544];
      }
      const float r = 1.f / (1.f + __expf(-(b2f(gir) + s0a)));
      const float z = 1.f / (1.f + __expf(-(b2f(giz) + s1a)));
      const float hu = ((mask >> eb) & 1u) ? 0.f : h_old;
      const float pre = b2f(gin) + r * (s2a + bhn_c);
      const float n = 1.f - 2.f / (1.f + __expf(2.f * pre));
      float hn = (1.f - z) * n + z * hu;
      hn = fminf(1.f, fmaxf(-1.f, hn));
      __builtin_nontemporal_store(hn, ys + ((size_t)tg * 128 + bglob) * 512 + colglob);
      // tagged bf16 publish to slot (tg+1)&1
      const uint32_t tagged = (((uint32_t)(tg + 1) & 0xFFFFu) << 16) | (uint32_t)f2bf(hn);
      uint32_t* hp = hxt + (size_t)((tg + 1) & 1) * 65536 + (size_t)bglob * 512 + colglob;
      __hip_atomic_store(hp, tagged, __ATOMIC_RELAXED, __HIP_MEMORY_SCOPE_AGENT);
      if (t == tc - 1) hbF[(size_t)bglob * 512 + colglob] = hn;   // f32 carry for next chunk
      h_old = hn;
    }
    if (t + 1 < tc) {
      // prefetch next step's gi + resets (drains at the canary barrier)
      const unsigned short* gp = gi + ((size_t)(t + 1) * 128 + bglob) * 1536 + colglob;
      uint32_t ngr = gp[0], ngz = gp[512], ngn = gp[1024];
      unsigned nmask = rmask16f(resets, rmode, tg + 1, rg * 16);
      const unsigned exp = (unsigned)(tg + 1) & 0xFFFFu;
      const size_t slotoff = (size_t)((tg + 1) & 1) * 65536;
      // ---- canary gate: wave 0, lanes 0-15 poll one word per producer ----
      if (wv == 0) {
        const uint32_t* cp = hxt + slotoff + (size_t)(rg * 16 + 15) * 512
                           + (lane & 15) * 32 + 31;
        bool ok = (lane >= 16);
        for (int it = 0; it < (1 << 14); ++it) {
          if (!ok)
            ok = ((__hip_atomic_load(cp, __ATOMIC_RELAXED,
                                     __HIP_MEMORY_SCOPE_AGENT) >> 16) == exp);
          if (__ballot(ok ? 0 : 1) == 0ull) break;
          __builtin_amdgcn_s_sleep(1);
        }
      }
      __syncthreads();  // gate: waves 1-7 idle here (quiet fabric); gi drained
      // ---- verify-fetch (authoritative, usually 1 iteration) ----
      pollTag(hxt + slotoff + (size_t)rg * 8192 + tid, exp, v);
      gir = ngr; giz = ngz; gin = ngn; mask = nmask;
    }
  }
}

// ---------------- launch ----------------
extern "C" void kernel_launch(void* const* d_in, const int* in_sizes, int n_in,
                              void* d_out, int out_size, void* d_ws, size_t ws_size,
                              hipStream_t stream) {
  const float* h0 = (const float*)d_in[0];
  const float* ins = (const float*)d_in[1];
  const int* rst = (const int*)d_in[2];
  const float* Wi = (const float*)d_in[3];
  const float* bi = (const float*)d_in[4];
  const float* Whrz = (const float*)d_in[5];
  const float* Whn = (const float*)d_in[6];
  const float* bhn = (const float*)d_in[7];
  float* ys = (float*)d_out;

  char* ws = (char*)d_ws;
  unsigned short* WiT = (unsigned short*)(ws);              // 1,572,864 B
  unsigned short* Wpk = (unsigned short*)(ws + 1572864);    // 1,572,864 B
  uint32_t* hxt = (uint32_t*)(ws + 3145728);                //   524,288 B ([2][128][512])
  float* hbF = (float*)(ws + 3670016);                      //   262,144 B ([128][512])
  int* flag = (int*)(ws + 3932160);                         //         4 B (rmode)
  const size_t gi_off = 3936256;
  unsigned short* gi = (unsigned short*)(ws + gi_off);

  size_t avail = (ws_size > gi_off) ? (ws_size - gi_off) : 0;
  long long tcap = (long long)(avail / (128ull * 1536ull * 2ull));
  int Tc = (int)((tcap > 1024) ? 1024 : tcap);
  Tc &= ~1;
  if (Tc < 2) Tc = 2;

  hipMemsetAsync(flag, 0, 4, stream);                                  // rmode
  hipMemsetAsync(hxt, 0, 524288, stream);        // both slots -> tag 0 (replay-safe)
  tag0<<<dim3(128), dim3(512), 0, stream>>>(h0, hxt, hbF);             // slot0 = h(0)
  prep<<<dim3(6144), dim3(256), 0, stream>>>(Wi, Whrz, Whn, WiT, Wpk);
  scanR<<<dim3(128), dim3(256), 0, stream>>>(rst, flag);

  for (int t0 = 0; t0 < 1024; t0 += Tc) {
    int tc = 1024 - t0;
    if (tc > Tc) tc = Tc;
    gemmA<<<dim3(12, tc), dim3(256), 0, stream>>>(ins + (size_t)t0 * 65536, WiT, bi, gi);
    rnnB<<<dim3(128), dim3(512), 0, stream>>>(gi, Wpk, bhn, rst, hxt, hbF, flag, ys, t0, tc);
  }
}

// Round 17
// 3140.469 us; speedup vs baseline: 2.1107x; 1.0961x over previous
//
#include <hip/hip_runtime.h>
#include <stdint.h>

// ScannedRNN: T=1024, B=128, D=512 GRU with resets + straight-through clip.
// prep (weight convert/pack) -> gemmA (gi = x@Wi+bi, bf16; DOUBLE-BUFFERED
// LDS, one barrier per K-step) -> rnnB (r13-proven: persistent 128-block
// recurrent kernel; Wh in VGPRs; tagged-word 2-slot relaxed-agent h
// exchange; canary gate + verify-fetch).

typedef float f32x4 __attribute__((ext_vector_type(4)));
typedef short s16x8 __attribute__((ext_vector_type(8)));

#define DD 512
#define BB 128
#define TT 1024

static __device__ __forceinline__ unsigned short f2bf(float f) {
  uint32_t u = __builtin_bit_cast(uint32_t, f);
  u = (u + 0x7fffu + ((u >> 16) & 1u)) >> 16;   // RNE
  return (unsigned short)u;
}
static __device__ __forceinline__ float b2f(uint32_t bits) {
  return __builtin_bit_cast(float, bits << 16);
}
static __device__ __forceinline__ s16x8 ldsfrag(const char* p) {
  return __builtin_bit_cast(s16x8, *reinterpret_cast<const uint4*>(p));
}
// HW RNE pack: lo16 = bf16(a), hi16 = bf16(b). Same rounding as f2bf.
static __device__ __forceinline__ uint32_t pk2(float a, float b) {
  uint32_t r;
  asm("v_cvt_pk_bf16_f32 %0, %1, %2" : "=v"(r) : "v"(a), "v"(b));
  return r;
}

// ---------------- prep: convert weights to bf16, packed layouts ----------------
__global__ void prep(const float* __restrict__ Wi, const float* __restrict__ Whrz,
                     const float* __restrict__ Whn,
                     unsigned short* __restrict__ WiT, unsigned short* __restrict__ Wpk) {
  int i = blockIdx.x * 256 + threadIdx.x;
  if (i < 786432) {
    int n = i >> 9, k = i & 511;
    WiT[i] = f2bf(Wi[(size_t)k * 1536 + n]);
  } else {
    int j = i - 786432;
    int ck = j >> 9;
    int k = j & 511;
    int cj = ck / 96, c96 = ck % 96;
    int g = c96 >> 5, cc = c96 & 31;
    float v = (g < 2) ? Whrz[(size_t)k * 1024 + g * 512 + cj * 32 + cc]
                      : Whn[(size_t)k * 512 + cj * 32 + cc];
    Wpk[j] = f2bf(v);
  }
}

// ---------------- tag0: mirror slot0 <- tagged(epoch 0) h0; f32 mirror <- h0 ----
__global__ void tag0(const float* __restrict__ h0, uint32_t* __restrict__ hxt,
                     float* __restrict__ hbF) {
  int i = blockIdx.x * 512 + threadIdx.x;   // 65536
  float v = h0[i];
  hxt[i] = (uint32_t)f2bf(v);               // tag 0
  hbF[i] = v;
}

// ---------------- resets dtype probe (bool bytes vs int32) ----------------
__global__ void scanR(const int* __restrict__ r, int* __restrict__ flag) {
  int i = blockIdx.x * 256 + threadIdx.x;       // 32768 ints = 131072 bytes, safe
  unsigned int v = (unsigned int)r[i];
  if (v > 1u) atomicOr(flag, 1);
}

// ---------------- gemmA: gi[M][1536] = x[M][512] @ Wi + bi (bf16 out) ----------------
// Double-buffered LDS: stage kt+1 into buf[p^1] while MFMAs read buf[p];
// ONE __syncthreads per K-step (8 total vs 16).
__global__ __launch_bounds__(256) void gemmA(const float* __restrict__ x,
                                             const unsigned short* __restrict__ WiT,
                                             const float* __restrict__ bi,
                                             unsigned short* __restrict__ gi) {
  __shared__ unsigned short Al[2][128 * 64];
  __shared__ unsigned short Bl[2][128 * 64];
  const int tid = threadIdx.x;
  const int lane = tid & 63;
  const int wv = tid >> 6;
  const int wm = wv >> 1, wn = wv & 1;
  const int n0 = blockIdx.x * 128;
  const int m0 = blockIdx.y * 128;

  const int sr = tid >> 1;
  const int sh = tid & 1;
  const float* xp = x + (size_t)(m0 + sr) * DD + sh * 32;
  const unsigned short* wp = WiT + (size_t)(n0 + sr) * DD + sh * 32;
  const int swz = (sr & 7) << 4;
  int soffs[4];
#pragma unroll
  for (int c = 0; c < 4; ++c) soffs[c] = sr * 128 + ((sh * 64 + c * 16) ^ swz);

  float bir[4];
#pragma unroll
  for (int j = 0; j < 4; ++j) bir[j] = bi[n0 + wn * 64 + j * 16 + (lane & 15)];

  f32x4 acc[4][4];
#pragma unroll
  for (int i = 0; i < 4; ++i)
#pragma unroll
    for (int j = 0; j < 4; ++j) acc[i][j] = (f32x4){0.f, 0.f, 0.f, 0.f};

  float4 xa[8];
  uint4 wa[4];
  // prologue: load kt=0, stage into buf 0, then prefetch kt=1
#pragma unroll
  for (int q = 0; q < 8; ++q) xa[q] = *reinterpret_cast<const float4*>(xp + q * 4);
#pragma unroll
  for (int c = 0; c < 4; ++c) wa[c] = *reinterpret_cast<const uint4*>(wp + c * 8);
#pragma unroll
  for (int c = 0; c < 4; ++c) {
    const float4 a = xa[2 * c], b = xa[2 * c + 1];
    uint4 u;
    u.x = pk2(a.x, a.y); u.y = pk2(a.z, a.w);
    u.z = pk2(b.x, b.y); u.w = pk2(b.z, b.w);
    *reinterpret_cast<uint4*>(reinterpret_cast<char*>(Al[0]) + soffs[c]) = u;
    *reinterpret_cast<uint4*>(reinterpret_cast<char*>(Bl[0]) + soffs[c]) = wa[c];
  }
#pragma unroll
  for (int q = 0; q < 8; ++q) xa[q] = *reinterpret_cast<const float4*>(xp + 64 + q * 4);
#pragma unroll
  for (int c = 0; c < 4; ++c) wa[c] = *reinterpret_cast<const uint4*>(wp + 64 + c * 8);

  int p = 0;
  for (int kt = 0; kt < 8; ++kt) {
    __syncthreads();   // buf[p] staged by all waves
#pragma unroll
    for (int kk = 0; kk < 2; ++kk) {
      s16x8 af[4], bfr[4];
      const int kb = kk * 64 + ((lane >> 4) << 4);
      const int sw = (lane & 7) << 4;
#pragma unroll
      for (int i = 0; i < 4; ++i) {
        const int row = wm * 64 + i * 16 + (lane & 15);
        af[i] = ldsfrag(reinterpret_cast<const char*>(Al[p]) + row * 128 + (kb ^ sw));
      }
#pragma unroll
      for (int j = 0; j < 4; ++j) {
        const int row = wn * 64 + j * 16 + (lane & 15);
        bfr[j] = ldsfrag(reinterpret_cast<const char*>(Bl[p]) + row * 128 + (kb ^ sw));
      }
#pragma unroll
      for (int i = 0; i < 4; ++i)
#pragma unroll
        for (int j = 0; j < 4; ++j)
          acc[i][j] = __builtin_amdgcn_mfma_f32_16x16x32_bf16(af[i], bfr[j], acc[i][j], 0, 0, 0);
    }
    if (kt < 7) {
      const int q2 = p ^ 1;
#pragma unroll
      for (int c = 0; c < 4; ++c) {
        const float4 a = xa[2 * c], b = xa[2 * c + 1];
        uint4 u;
        u.x = pk2(a.x, a.y); u.y = pk2(a.z, a.w);
        u.z = pk2(b.x, b.y); u.w = pk2(b.z, b.w);
        *reinterpret_cast<uint4*>(reinterpret_cast<char*>(Al[q2]) + soffs[c]) = u;
        *reinterpret_cast<uint4*>(reinterpret_cast<char*>(Bl[q2]) + soffs[c]) = wa[c];
      }
      if (kt < 6) {   // prefetch kt+2 (drains during next iteration's MFMA)
#pragma unroll
        for (int q = 0; q < 8; ++q)
          xa[q] = *reinterpret_cast<const float4*>(xp + (kt + 2) * 64 + q * 4);
#pragma unroll
        for (int c = 0; c < 4; ++c)
          wa[c] = *reinterpret_cast<const uint4*>(wp + (kt + 2) * 64 + c * 8);
      }
      p = q2;
    }
  }
#pragma unroll
  for (int i = 0; i < 4; ++i) {
    const int gr0 = m0 + wm * 64 + i * 16 + ((lane >> 4) << 2);
#pragma unroll
    for (int j = 0; j < 4; ++j) {
      const int gc = n0 + wn * 64 + j * 16 + (lane & 15);
#pragma unroll
      for (int r = 0; r < 4; ++r) {
        float s = acc[i][j][r] + bir[j];
        gi[(size_t)(gr0 + r) * 1536 + gc] = (unsigned short)pk2(s, s);
      }
    }
  }
}

// ---------------- rnnB helpers ----------------
static __device__ __forceinline__ unsigned rmask16f(const int* resets, int rmode,
                                                    long long tg, int row0) {
  unsigned m = 0;
  if (rmode) {
    const unsigned char* rb = reinterpret_cast<const unsigned char*>(resets);
    uint4 u = *reinterpret_cast<const uint4*>(rb + (size_t)tg * 128 + row0);
    unsigned w0 = u.x, w1 = u.y, w2 = u.z, w3 = u.w;
#pragma unroll
    for (int b = 0; b < 4; ++b) {
      if ((w0 >> (8 * b)) & 0xFFu) m |= 1u << (0 + b);
      if ((w1 >> (8 * b)) & 0xFFu) m |= 1u << (4 + b);
      if ((w2 >> (8 * b)) & 0xFFu) m |= 1u << (8 + b);
      if ((w3 >> (8 * b)) & 0xFFu) m |= 1u << (12 + b);
    }
  } else {
    const uint4* p = reinterpret_cast<const uint4*>(resets + (size_t)tg * 128 + row0);
#pragma unroll
    for (int q = 0; q < 4; ++q) {
      uint4 u = p[q];
      if (u.x) m |= 1u << (q * 4 + 0);
      if (u.y) m |= 1u << (q * 4 + 1);
      if (u.z) m |= 1u << (q * 4 + 2);
      if (u.w) m |= 1u << (q * 4 + 3);
    }
  }
  return m;
}

// batched branch-free tag poll: 16 coalesced agent loads -> single wait ->
// ballot; v[i] = low 16 bits once tag matches. (authoritative)
static __device__ __forceinline__ void pollTag(const uint32_t* src, unsigned exp,
                                               unsigned short (&v)[16]) {
  for (int it = 0; it < (1 << 16); ++it) {
    uint32_t u[16];
#pragma unroll
    for (int i = 0; i < 16; ++i)
      u[i] = __hip_atomic_load(src + (size_t)i * 512,
                               __ATOMIC_RELAXED, __HIP_MEMORY_SCOPE_AGENT);
    unsigned bad = 0;
#pragma unroll
    for (int i = 0; i < 16; ++i) bad |= ((u[i] >> 16) ^ exp);
    if (__ballot(bad != 0u) == 0ull) {
#pragma unroll
      for (int i = 0; i < 16; ++i) v[i] = (unsigned short)u[i];
      return;
    }
    __builtin_amdgcn_s_sleep(1);
  }
#pragma unroll
  for (int i = 0; i < 16; ++i) v[i] = 0;   // watchdog fall-through (unreachable)
}

// ---------------- rnnB: persistent recurrent kernel (r13-proven) ----------------
// 128 blocks = 16 col-blocks (cj) x 8 row groups (rg). Wh slice in VGPRs.
// h exchange: hxt [2][128][512] u32 = (epoch16<<16)|bf16(h), slot (tg+1)&1.
// 2-slot + exact tag is overwrite-safe. Poll = canary gate (wave 0 polls one
// word per producer; other waves park at barrier -> fabric stays quiet) then
// a single verify-fetch pass (authoritative pollTag).
__global__ __launch_bounds__(512) void rnnB(const unsigned short* __restrict__ gi,
                                            const unsigned short* __restrict__ Wpk,
                                            const float* __restrict__ bhn,
                                            const int* __restrict__ resets,
                                            uint32_t* hxt,                 // [2][128][512]
                                            float* hbF,                    // [128][512]
                                            const int* __restrict__ rmodep,
                                            float* __restrict__ ys,
                                            int t0, int tc) {
  __shared__ char Hlb[16384];     // h(t) bf16 [16 rows][512 cols], xor-swizzled
  __shared__ float ax[6528];      // partials [8][3][16*17]

  const int tid = threadIdx.x;
  const int lane = tid & 63;
  const int wv = tid >> 6;
  const int w = wv & 1, ks = wv >> 1;
  const int cj = blockIdx.x >> 3, rg = blockIdx.x & 7;
  const int ec = tid & 31, eb = tid >> 5;          // elementwise: col-in-32, row-in-16
  const int bglob = rg * 16 + eb;
  const int colglob = cj * 32 + ec;
  const int rmode = *rmodep;

  // ---- Wh fragments -> registers (once per launch) ----
  uint4 wreg[3][4];
  {
    const unsigned short* wbase = Wpk + (size_t)cj * 96 * 512
                                + (size_t)(w * 16 + (lane & 15)) * 512
                                + ks * 128 + (lane >> 4) * 8;
#pragma unroll
    for (int g = 0; g < 3; ++g)
#pragma unroll
      for (int kk = 0; kk < 4; ++kk)
        wreg[g][kk] = *reinterpret_cast<const uint4*>(wbase + g * 32 * 512 + kk * 32);
  }

  const float bhn_c = bhn[colglob];
  float h_old = hbF[(size_t)bglob * 512 + colglob];   // f32 carry at chunk start

  // ---- initial h(t0) bf16 panel: poll slot t0&1 for tag t0 (already present) ----
  unsigned short v[16];
  pollTag(hxt + (size_t)(t0 & 1) * 65536 + (size_t)rg * 8192 + tid, (unsigned)t0 & 0xFFFFu, v);

  unsigned mask = rmask16f(resets, rmode, t0, rg * 16);
  uint32_t gir, giz, gin;
  {
    const unsigned short* gp = gi + (size_t)bglob * 1536 + colglob;  // chunk-local t=0
    gir = gp[0]; giz = gp[512]; gin = gp[1024];
  }

  // precomputed LDS stage offsets (thread column tid, row i)
  int soff[16];
#pragma unroll
  for (int i = 0; i < 16; ++i)
    soff[i] = i * 1024 + (((((tid * 2) >> 4) ^ (i & 7)) << 4) | ((tid & 7) * 2));

  for (int t = 0; t < tc; ++t) {
    const long long tg = t0 + t;
    // ---- stage Hl: thread owns column tid, rows 0..15; reset-masked ----
#pragma unroll
    for (int i = 0; i < 16; ++i) {
      unsigned short x = ((mask >> i) & 1u) ? (unsigned short)0 : v[i];
      *reinterpret_cast<unsigned short*>(Hlb + soff[i]) = x;
    }
    __syncthreads();  // B1: Hl ready
    // ---- MFMA: W frags from VGPR, H frags from LDS ----
    f32x4 acc[3];
#pragma unroll
    for (int g = 0; g < 3; ++g) acc[g] = (f32x4){0.f, 0.f, 0.f, 0.f};
    {
      const int rowb = lane & 15;
      const char* hrow = Hlb + rowb * 1024;
      const int hsw = (rowb & 7) << 4;
      const int kplusB = (lane >> 4) << 4;
      s16x8 hfrag[4];
#pragma unroll
      for (int kk = 0; kk < 4; ++kk) {
        const int kbB = (ks * 128 + kk * 32) * 2 + kplusB;
        hfrag[kk] = ldsfrag(hrow + (kbB ^ hsw));
      }
#pragma unroll
      for (int g = 0; g < 3; ++g)
#pragma unroll
        for (int kk = 0; kk < 4; ++kk)
          acc[g] = __builtin_amdgcn_mfma_f32_16x16x32_bf16(
              __builtin_bit_cast(s16x8, wreg[g][kk]), hfrag[kk], acc[g], 0, 0, 0);
    }
    {  // partials -> LDS (padded stride 17)
      const int mh = (lane >> 4) << 2, nn = lane & 15;
#pragma unroll
      for (int g = 0; g < 3; ++g) {
        float* dst = ax + ((ks * 2 + w) * 3 + g) * 272 + nn;
#pragma unroll
        for (int r = 0; r < 4; ++r) dst[(mh + r) * 17] = acc[g][r];
      }
    }
    __syncthreads();  // B2: ax ready; also fences Hl reads vs next stage
    // ---- elementwise GRU update: one (row eb, col ec) per thread ----
    {
      const int wc = ec >> 4, mc = ec & 15;
      float s0a = 0.f, s1a = 0.f, s2a = 0.f;
#pragma unroll
      for (int k2 = 0; k2 < 4; ++k2) {
        const float* p = ax + ((k2 * 2 + wc) * 3) * 272 + mc * 17 + eb;
        s0a += p[0]; s1a += p[272]; s2a += p[544];
      }
      const float r = 1.f / (1.f + __expf(-(b2f(gir) + s0a)));
      const float z = 1.f / (1.f + __expf(-(b2f(giz) + s1a)));
      const float hu = ((mask >> eb) & 1u) ? 0.f : h_old;
      const float pre = b2f(gin) + r * (s2a + bhn_c);
      const float n = 1.f - 2.f / (1.f + __expf(2.f * pre));
      float hn = (1.f - z) * n + z * hu;
      hn = fminf(1.f, fmaxf(-1.f, hn));
      __builtin_nontemporal_store(hn, ys + ((size_t)tg * 128 + bglob) * 512 + colglob);
      // tagged bf16 publish to slot (tg+1)&1
      const uint32_t tagged = (((uint32_t)(tg + 1) & 0xFFFFu) << 16) | (uint32_t)f2bf(hn);
      uint32_t* hp = hxt + (size_t)((tg + 1) & 1) * 65536 + (size_t)bglob * 512 + colglob;
      __hip_atomic_store(hp, tagged, __ATOMIC_RELAXED, __HIP_MEMORY_SCOPE_AGENT);
      if (t == tc - 1) hbF[(size_t)bglob * 512 + colglob] = hn;   // f32 carry for next chunk
      h_old = hn;
    }
    if (t + 1 < tc) {
      // prefetch next step's gi + resets (drains at the canary barrier)
      const unsigned short* gp = gi + ((size_t)(t + 1) * 128 + bglob) * 1536 + colglob;
      uint32_t ngr = gp[0], ngz = gp[512], ngn = gp[1024];
      unsigned nmask = rmask16f(resets, rmode, tg + 1, rg * 16);
      const unsigned exp = (unsigned)(tg + 1) & 0xFFFFu;
      const size_t slotoff = (size_t)((tg + 1) & 1) * 65536;
      // ---- canary gate: wave 0, lanes 0-15 poll one word per producer ----
      if (wv == 0) {
        const uint32_t* cp = hxt + slotoff + (size_t)(rg * 16 + 15) * 512
                           + (lane & 15) * 32 + 31;
        bool ok = (lane >= 16);
        for (int it = 0; it < (1 << 14); ++it) {
          if (!ok)
            ok = ((__hip_atomic_load(cp, __ATOMIC_RELAXED,
                                     __HIP_MEMORY_SCOPE_AGENT) >> 16) == exp);
          if (__ballot(ok ? 0 : 1) == 0ull) break;
          __builtin_amdgcn_s_sleep(1);
        }
      }
      __syncthreads();  // gate: waves 1-7 idle here (quiet fabric); gi drained
      // ---- verify-fetch (authoritative, usually 1 iteration) ----
      pollTag(hxt + slotoff + (size_t)rg * 8192 + tid, exp, v);
      gir = ngr; giz = ngz; gin = ngn; mask = nmask;
    }
  }
}

// ---------------- launch ----------------
extern "C" void kernel_launch(void* const* d_in, const int* in_sizes, int n_in,
                              void* d_out, int out_size, void* d_ws, size_t ws_size,
                              hipStream_t stream) {
  const float* h0 = (const float*)d_in[0];
  const float* ins = (const float*)d_in[1];
  const int* rst = (const int*)d_in[2];
  const float* Wi = (const float*)d_in[3];
  const float* bi = (const float*)d_in[4];
  const float* Whrz = (const float*)d_in[5];
  const float* Whn = (const float*)d_in[6];
  const float* bhn = (const float*)d_in[7];
  float* ys = (float*)d_out;

  char* ws = (char*)d_ws;
  unsigned short* WiT = (unsigned short*)(ws);              // 1,572,864 B
  unsigned short* Wpk = (unsigned short*)(ws + 1572864);    // 1,572,864 B
  uint32_t* hxt = (uint32_t*)(ws + 3145728);                //   524,288 B ([2][128][512])
  float* hbF = (float*)(ws + 3670016);                      //   262,144 B ([128][512])
  int* flag = (int*)(ws + 3932160);                         //         4 B (rmode)
  const size_t gi_off = 3936256;
  unsigned short* gi = (unsigned short*)(ws + gi_off);

  size_t avail = (ws_size > gi_off) ? (ws_size - gi_off) : 0;
  long long tcap = (long long)(avail / (128ull * 1536ull * 2ull));
  int Tc = (int)((tcap > 1024) ? 1024 : tcap);
  Tc &= ~1;
  if (Tc < 2) Tc = 2;

  hipMemsetAsync(flag, 0, 4, stream);                                  // rmode
  hipMemsetAsync(hxt, 0, 524288, stream);        // both slots -> tag 0 (replay-safe)
  tag0<<<dim3(128), dim3(512), 0, stream>>>(h0, hxt, hbF);             // slot0 = h(0)
  prep<<<dim3(6144), dim3(256), 0, stream>>>(Wi, Whrz, Whn, WiT, Wpk);
  scanR<<<dim3(128), dim3(256), 0, stream>>>(rst, flag);

  for (int t0 = 0; t0 < 1024; t0 += Tc) {
    int tc = 1024 - t0;
    if (tc > Tc) tc = Tc;
    gemmA<<<dim3(12, tc), dim3(256), 0, stream>>>(ins + (size_t)t0 * 65536, WiT, bi, gi);
    rnnB<<<dim3(128), dim3(512), 0, stream>>>(gi, Wpk, bhn, rst, hxt, hbF, flag, ys, t0, tc);
  }
}